// Round 4
// baseline (479.316 us; speedup 1.0000x reference)
//
#include <hip/hip_runtime.h>
#include <hip/hip_bf16.h>

typedef __bf16 bf16_t;
typedef __bf16 bf16x8 __attribute__((ext_vector_type(8)));
typedef __bf16 bf16x4 __attribute__((ext_vector_type(4)));
typedef float  f32x4  __attribute__((ext_vector_type(4)));

#define T_TOK 1024
#define DDIM  1024
#define FDIM  2048
#define NEXP  16
#define MAXR  192   // max tokens per expert (cnt ~128 +/- 11)

// ---------------- workspace layout (bytes), peak 21.1 MB ----------------
// [0, 64)        : int cnt[NEXP]                (memset each call)
// [1024, +64K)   : int   entry[NEXP][T_TOK]     (value = t*2 + slot)
// [66560, +64K)  : float entry_w[NEXP][T_TOK]
// [132096, +8M)  : OVERLAY: xg[NEXP][MAXR][DDIM] bf16 (gather..ffn1)
//                  then    partial[2][T_TOK][DDIM] f32 (ffn2..add, memset 0)
// [8520704, +12.6M): bf16 fuse[NEXP][MAXR][FDIM]
#define WS_ENTRY_OFF   1024
#define WS_ENTRYW_OFF  66560
#define WS_XG_OFF      132096
#define WS_PART_OFF    132096
#define WS_FUSE_OFF    8520704

// ---------------- router: one block (64 thr) per token ----------------
__global__ __launch_bounds__(64) void router_kernel(
    const float* __restrict__ x, const float* __restrict__ rw,
    int* __restrict__ cnt, int* __restrict__ entry, float* __restrict__ entry_w)
{
    const int t = blockIdx.x;
    const int lane = threadIdx.x;
    float acc[NEXP];
#pragma unroll
    for (int e = 0; e < NEXP; ++e) acc[e] = 0.f;
#pragma unroll
    for (int i = 0; i < DDIM / 64; ++i) {
        const int d = lane + i * 64;
        const float xv = x[(size_t)t * DDIM + d];
        const float* r = rw + (size_t)d * NEXP;
#pragma unroll
        for (int e = 0; e < NEXP; ++e) acc[e] += xv * r[e];
    }
#pragma unroll
    for (int e = 0; e < NEXP; ++e) {
        float v = acc[e];
        for (int off = 32; off > 0; off >>= 1) v += __shfl_down(v, off);
        acc[e] = v;
    }
    if (lane == 0) {
        int i0 = -1, i1 = -1;
        float v0 = -1e30f, v1 = -1e30f;
#pragma unroll
        for (int e = 0; e < NEXP; ++e) {
            const float v = acc[e];
            if (v > v0)      { v1 = v0; i1 = i0; v0 = v; i0 = e; }
            else if (v > v1) { v1 = v;  i1 = e; }
        }
        const float e1 = __expf(v1 - v0);
        const float w0 = 1.f / (1.f + e1);
        const float w1 = e1 / (1.f + e1);
        int p = atomicAdd(&cnt[i0], 1);
        entry[i0 * T_TOK + p] = t * 2 + 0;
        entry_w[i0 * T_TOK + p] = w0;
        p = atomicAdd(&cnt[i1], 1);
        entry[i1 * T_TOK + p] = t * 2 + 1;
        entry_w[i1 * T_TOK + p] = w1;
    }
}

// ---------------- gather: x -> expert-local bf16 xg[e][i][d] (zero-padded) ----
// grid (NEXP, MAXR/8), 256 thr; one float4 per thread per row (coalesced).
__global__ __launch_bounds__(256) void gather_kernel(
    const float* __restrict__ x, const int* __restrict__ cnt,
    const int* __restrict__ entry, bf16_t* __restrict__ xg)
{
    const int e  = blockIdx.x;
    const int i0 = blockIdx.y * 8;
    const int tid = threadIdx.x;
    int n_tok = cnt[e]; if (n_tok > MAXR) n_tok = MAXR;
#pragma unroll
    for (int rr = 0; rr < 8; ++rr) {
        const int i = i0 + rr;
        bf16x4 v4;
        v4[0] = (bf16_t)0.f; v4[1] = (bf16_t)0.f; v4[2] = (bf16_t)0.f; v4[3] = (bf16_t)0.f;
        if (i < n_tok) {
            const int tok = entry[e * T_TOK + i] >> 1;
            const float4 v = *(const float4*)(x + (size_t)tok * DDIM + tid * 4);
            v4[0] = (bf16_t)v.x; v4[1] = (bf16_t)v.y; v4[2] = (bf16_t)v.z; v4[3] = (bf16_t)v.w;
        }
        *(bf16x4*)(xg + ((size_t)e * MAXR + i) * DDIM + tid * 4) = v4;
    }
}

// ---------------- phase 1: gating+up MFMA + silu-fuse ----------------
// grid (NEXP, FDIM/32) = 1024 blocks, 256 thr, 4 blocks/CU.
// BM=192 (all tokens), BN=32, BK=32. A direct global->reg; B dbuf LDS.
// Zero-padded xg rows make padded outputs exactly 0 -> no masking needed.
__global__ __launch_bounds__(256, 4) void ffn1_kernel(
    const bf16_t* __restrict__ xg,
    const float* __restrict__ wg, const float* __restrict__ wu,
    bf16_t* __restrict__ fuse)
{
    const int e  = blockIdx.x;
    const int f0 = blockIdx.y * 32;

    __shared__ __align__(16) bf16_t Bs[2][2][32][40];  // [buf][mat][n][k+pad] 10 KB

    const int tid  = threadIdx.x;
    const int wave = tid >> 6;
    const int lane = tid & 63;
    const int r    = lane & 15;
    const int q    = lane >> 4;

    // B staging role: waves 0-1 -> gating, waves 2-3 -> up
    const int mat  = tid >> 7;
    const int bn   = tid & 31;
    const int koct = (tid >> 5) & 3;
    const float* w_p = (mat ? wu : wg) + (size_t)e * DDIM * FDIM
                     + (size_t)(koct * 8) * FDIM + f0 + bn;

    const bf16_t* xg_e = xg + (size_t)e * MAXR * DDIM + q * 8;

    // prologue: B(0) regs, A(0) frags
    float rb[8];
#pragma unroll
    for (int j = 0; j < 8; ++j) rb[j] = w_p[(size_t)j * FDIM];

    bf16x8 af[2][3];
#pragma unroll
    for (int mt = 0; mt < 3; ++mt)
        af[0][mt] = *(const bf16x8*)(xg_e + (size_t)(wave * 48 + mt * 16 + r) * DDIM);

    f32x4 accg[3][2], accu[3][2];
#pragma unroll
    for (int a = 0; a < 3; ++a)
#pragma unroll
        for (int b = 0; b < 2; ++b) {
            accg[a][b] = (f32x4){0.f, 0.f, 0.f, 0.f};
            accu[a][b] = (f32x4){0.f, 0.f, 0.f, 0.f};
        }

    for (int i = 0; i < 32; ++i) {
        const int buf = i & 1;
        // pack B(i) -> LDS (one b128 per thread)
        bf16x8 pb;
#pragma unroll
        for (int j = 0; j < 8; ++j) pb[j] = (bf16_t)rb[j];
        *(bf16x8*)&Bs[buf][mat][bn][koct * 8] = pb;
        __syncthreads();
        if (i < 31) {
            // prefetch B(i+1) + A(i+1)
            w_p += (size_t)32 * FDIM;
#pragma unroll
            for (int j = 0; j < 8; ++j) rb[j] = w_p[(size_t)j * FDIM];
            const int kk = (i + 1) * 32;
#pragma unroll
            for (int mt = 0; mt < 3; ++mt)
                af[buf ^ 1][mt] = *(const bf16x8*)(xg_e + (size_t)(wave * 48 + mt * 16 + r) * DDIM + kk);
        }
        bf16x8 bg[2], bu[2];
#pragma unroll
        for (int nt = 0; nt < 2; ++nt) {
            bg[nt] = *(const bf16x8*)&Bs[buf][0][nt * 16 + r][q * 8];
            bu[nt] = *(const bf16x8*)&Bs[buf][1][nt * 16 + r][q * 8];
        }
#pragma unroll
        for (int mt = 0; mt < 3; ++mt)
#pragma unroll
            for (int nt = 0; nt < 2; ++nt) {
                accg[mt][nt] = __builtin_amdgcn_mfma_f32_16x16x32_bf16(af[buf][mt], bg[nt], accg[mt][nt], 0, 0, 0);
                accu[mt][nt] = __builtin_amdgcn_mfma_f32_16x16x32_bf16(af[buf][mt], bu[nt], accu[mt][nt], 0, 0, 0);
            }
    }

    // epilogue: silu(g)*u -> fuse[e][m][f] (padded rows are exact zeros)
    bf16_t* fuse_e = fuse + (size_t)e * MAXR * FDIM + f0;
#pragma unroll
    for (int mt = 0; mt < 3; ++mt)
#pragma unroll
        for (int j = 0; j < 4; ++j) {
            const int m = wave * 48 + mt * 16 + q * 4 + j;
#pragma unroll
            for (int nt = 0; nt < 2; ++nt) {
                const float g = accg[mt][nt][j];
                const float u = accu[mt][nt][j];
                const float h = (g / (1.f + __expf(-g))) * u;
                fuse_e[(size_t)m * FDIM + nt * 16 + r] = (bf16_t)h;
            }
        }
}

// ---------------- phase 2: down MFMA, weighted -> partial (atomic) ---------
// grid (NEXP, DDIM/32, 2 k-halves) = 1024 blocks, 4 blocks/CU.
// BM=192, BN=32, BK=64 per barrier (two 32-k MFMA substeps).
__global__ __launch_bounds__(256, 4) void ffn2_kernel(
    const bf16_t* __restrict__ fuse, const float* __restrict__ wd,
    const int* __restrict__ cnt, const int* __restrict__ entry,
    const float* __restrict__ entry_w, float* __restrict__ partial)
{
    const int e  = blockIdx.x;
    const int d0 = blockIdx.y * 32;
    const int kh = blockIdx.z;           // k-half [kh*1024, +1024)
    int n_tok = cnt[e]; if (n_tok > MAXR) n_tok = MAXR;

    __shared__ __align__(16) bf16_t Bs[2][32][72];  // [buf][n][64k + 8 pad] 9 KB
    __shared__ int   sem[MAXR];
    __shared__ float sw[MAXR];

    const int tid  = threadIdx.x;
    const int wave = tid >> 6;
    const int lane = tid & 63;
    const int r    = lane & 15;
    const int q    = lane >> 4;

    const int bn   = tid & 31;
    const int koct = tid >> 5;           // 0..7 -> 64 k per iter
    const float* wd_p = wd + (size_t)e * FDIM * DDIM
                      + (size_t)(kh * 1024 + koct * 8) * DDIM + d0 + bn;
    const bf16_t* fu_e = fuse + (size_t)e * MAXR * FDIM + kh * 1024 + q * 8;

    if (tid < MAXR) {
        sem[tid] = (tid < n_tok) ? entry[e * T_TOK + tid] : -1;
        sw[tid]  = (tid < n_tok) ? entry_w[e * T_TOK + tid] : 0.f;
    }

    // prologue
    float rb[8];
#pragma unroll
    for (int j = 0; j < 8; ++j) rb[j] = wd_p[(size_t)j * DDIM];

    bf16x8 af[2][2][3];   // [buf][substep][mt]
#pragma unroll
    for (int s = 0; s < 2; ++s)
#pragma unroll
        for (int mt = 0; mt < 3; ++mt)
            af[0][s][mt] = *(const bf16x8*)(fu_e + (size_t)(wave * 48 + mt * 16 + r) * FDIM + s * 32);

    f32x4 acc[3][2];
#pragma unroll
    for (int a = 0; a < 3; ++a)
#pragma unroll
        for (int b = 0; b < 2; ++b) acc[a][b] = (f32x4){0.f, 0.f, 0.f, 0.f};

    for (int i = 0; i < 16; ++i) {
        const int buf = i & 1;
        bf16x8 pb;
#pragma unroll
        for (int j = 0; j < 8; ++j) pb[j] = (bf16_t)rb[j];
        *(bf16x8*)&Bs[buf][bn][koct * 8] = pb;
        __syncthreads();
        if (i < 15) {
            wd_p += (size_t)64 * DDIM;
#pragma unroll
            for (int j = 0; j < 8; ++j) rb[j] = wd_p[(size_t)j * DDIM];
            const int kk = (i + 1) * 64;
#pragma unroll
            for (int s = 0; s < 2; ++s)
#pragma unroll
                for (int mt = 0; mt < 3; ++mt)
                    af[buf ^ 1][s][mt] = *(const bf16x8*)(fu_e + (size_t)(wave * 48 + mt * 16 + r) * FDIM + kk + s * 32);
        }
#pragma unroll
        for (int s = 0; s < 2; ++s) {
            bf16x8 bb[2];
#pragma unroll
            for (int nt = 0; nt < 2; ++nt)
                bb[nt] = *(const bf16x8*)&Bs[buf][nt * 16 + r][s * 32 + q * 8];
#pragma unroll
            for (int mt = 0; mt < 3; ++mt)
#pragma unroll
                for (int nt = 0; nt < 2; ++nt)
                    acc[mt][nt] = __builtin_amdgcn_mfma_f32_16x16x32_bf16(af[buf][s][mt], bb[nt], acc[mt][nt], 0, 0, 0);
        }
    }

    // epilogue: weighted atomic accumulate (2 k-half writers per element)
#pragma unroll
    for (int mt = 0; mt < 3; ++mt)
#pragma unroll
        for (int j = 0; j < 4; ++j) {
            const int m = wave * 48 + mt * 16 + q * 4 + j;
            const int em = sem[m];
            if (em < 0) continue;
            const int t = em >> 1;
            const int slot = em & 1;
            const float w = sw[m];
            float* dst = partial + ((size_t)slot * T_TOK + t) * DDIM + d0;
#pragma unroll
            for (int nt = 0; nt < 2; ++nt)
                atomicAdd(&dst[nt * 16 + r], acc[mt][nt][j] * w);
        }
}

// ---------------- phase 3: out = partial[0] + partial[1] ----------------
__global__ __launch_bounds__(256) void add_kernel(
    const float* __restrict__ partial, float* __restrict__ out)
{
    const int i = blockIdx.x * blockDim.x + threadIdx.x;   // over T*D/4
    const float4 a = ((const float4*)partial)[i];
    const float4 b = ((const float4*)(partial + (size_t)T_TOK * DDIM))[i];
    float4 o;
    o.x = a.x + b.x; o.y = a.y + b.y; o.z = a.z + b.z; o.w = a.w + b.w;
    ((float4*)out)[i] = o;
}

extern "C" void kernel_launch(void* const* d_in, const int* in_sizes, int n_in,
                              void* d_out, int out_size, void* d_ws, size_t ws_size,
                              hipStream_t stream) {
    const float* x  = (const float*)d_in[0];
    const float* rw = (const float*)d_in[1];
    const float* wg = (const float*)d_in[2];
    const float* wu = (const float*)d_in[3];
    const float* wd = (const float*)d_in[4];
    float* out = (float*)d_out;

    char* ws = (char*)d_ws;
    int*    cnt     = (int*)ws;
    int*    entry   = (int*)(ws + WS_ENTRY_OFF);
    float*  entry_w = (float*)(ws + WS_ENTRYW_OFF);
    bf16_t* xg      = (bf16_t*)(ws + WS_XG_OFF);
    float*  partial = (float*)(ws + WS_PART_OFF);   // overlays xg (disjoint lifetime)
    bf16_t* fuse    = (bf16_t*)(ws + WS_FUSE_OFF);

    hipMemsetAsync(cnt, 0, 64, stream);

    router_kernel<<<T_TOK, 64, 0, stream>>>(x, rw, cnt, entry, entry_w);

    gather_kernel<<<dim3(NEXP, MAXR / 8), 256, 0, stream>>>(x, cnt, entry, xg);

    ffn1_kernel<<<dim3(NEXP, FDIM / 32), 256, 0, stream>>>(xg, wg, wu, fuse);

    // partial must be zero before atomic accumulation (ws is poisoned 0xAA)
    hipMemsetAsync(partial, 0, (size_t)2 * T_TOK * DDIM * sizeof(float), stream);

    ffn2_kernel<<<dim3(NEXP, DDIM / 32, 2), 256, 0, stream>>>(
        fuse, wd, cnt, entry, entry_w, partial);

    add_kernel<<<(T_TOK * DDIM / 4) / 256, 256, 0, stream>>>(partial, out);
}